// Round 9
// baseline (122.479 us; speedup 1.0000x reference)
//
#include <hip/hip_runtime.h>

// Problem constants (fixed by reference)
#define GS    256
#define PARAM 128
#define KC    32
#define I1    64
#define I2    32
#define PK    96        // PARAM - KC
#define B_    4
#define NROWS (B_ * GS) // 1024
#define EPS   1e-3f
#define KDIV_INV (1.0f / 16.0f)

// Workspace layout (float offsets)
constexpr int U_OFF   = 0;                   // NROWS*I1
constexpr int W_OFF   = NROWS * I1;
constexpr int M2F_OFF = 2 * NROWS * I1;      // I1*I2
constexpr int C2_OFF  = M2F_OFF + I1 * I2;   // I2
constexpr int M3F_OFF = C2_OFF + I2;         // I2*PK
constexpr int C3_OFF  = M3F_OFF + I2 * PK;   // PK
constexpr int C1_OFF  = C3_OFF + PK;         // I1

__device__ __forceinline__ float rdlane(float v, int l) {
    return __uint_as_float(__builtin_amdgcn_readlane(__float_as_uint(v), l));
}

// Kernel A: one block per row. 256 thr = 64 i-lanes x 4 quarter-dots.
// u = val.(M1top - M1bot) = T - W; compute T and W (1 load per MAC each).
__global__ __launch_bounds__(256) void glmlp_precompute(
    const float* __restrict__ val, const float* __restrict__ M1,
    const float* __restrict__ B1,
    const float* __restrict__ M2, const float* __restrict__ B2,
    const float* __restrict__ M3, const float* __restrict__ B3,
    const float* __restrict__ g1, const float* __restrict__ b1,
    const float* __restrict__ m1, const float* __restrict__ v1,
    const float* __restrict__ g2, const float* __restrict__ b2,
    const float* __restrict__ m2, const float* __restrict__ v2,
    const float* __restrict__ g3, const float* __restrict__ b3,
    const float* __restrict__ m3, const float* __restrict__ v3,
    float* __restrict__ ws, float* __restrict__ out)
{
    const int blk = blockIdx.x;
    const int t = threadIdx.x;

    if (blk < NROWS) {
        __shared__ float vrow[PARAM];
        __shared__ float red[4][I1];
        const int r = blk;
        if (t < PARAM) vrow[t] = val[r * PARAM + t];
        // exact copy: con = val[:, :, :KC] (direct from global; no barrier dep)
        if (t < KC) out[r * PARAM + t] = val[r * PARAM + t];
        __syncthreads();

        const int i = t & (I1 - 1);
        const int q = t >> 6;                         // 0..3
        // q=0,1 -> T (M1 top half); q=2,3 -> W (M1 bottom half)
        const float* __restrict__ Mb = M1 + ((q >> 1) ? (PARAM * I1) : 0);
        const int p0 = (q & 1) * 64;
        float aa = 0.f, bb = 0.f;                     // dual chains (dep 32)
        #pragma unroll 8
        for (int p = 0; p < 64; p += 2) {
            aa = fmaf(vrow[p0 + p],     Mb[(p0 + p) * I1 + i],     aa);
            bb = fmaf(vrow[p0 + p + 1], Mb[(p0 + p + 1) * I1 + i], bb);
        }
        red[q][i] = aa + bb;
        __syncthreads();

        if (q == 0) {
            const float T  = red[0][i] + red[1][i];
            const float Wv = red[2][i] + red[3][i];
            const float s1 = g1[i] * rsqrtf(v1[i] + EPS);
            ws[U_OFF + r * I1 + i] = (T - Wv) * s1;
            ws[W_OFF + r * I1 + i] = Wv * s1;
        }
    } else {
        // BN folding block
        if (t < I1) {
            const float s1 = g1[t] * rsqrtf(v1[t] + EPS);
            ws[C1_OFF + t] = B1[t] * s1 + b1[t] - m1[t] * s1;
        }
        if (t < I2) {
            const float s2 = g2[t] * rsqrtf(v2[t] + EPS);
            ws[C2_OFF + t] = B2[t] * s2 + b2[t] - m2[t] * s2;
        }
        if (t < PK) {
            const float s3 = g3[t] * rsqrtf(v3[t] + EPS);
            ws[C3_OFF + t] = B3[t] * s3 + b3[t] - m3[t] * s3;
        }
        for (int idx = t; idx < I1 * I2; idx += 256) {
            const int j = idx & (I2 - 1);
            const float s2 = g2[j] * rsqrtf(v2[j] + EPS);
            ws[M2F_OFF + idx] = M2[idx] * s2;
        }
        for (int idx = t; idx < I2 * PK; idx += 256) {
            const int k = idx % PK;
            const float s3 = g3[k] * rsqrtf(v3[k] + EPS);
            ws[M3F_OFF + idx] = M3[idx] * s3;
        }
    }
}

// Kernel B: WAVE-per-row; 256 blocks x 4 waves; ZERO LDS, ZERO barriers.
// Mask compaction via __ballot + scalar ctz iteration (no atomics).
// All cross-lane broadcasts via v_readlane; weights register-resident:
//   lane (h=lane>>5, j=lane&31): m2col[s]=M2f[s][j]; m3a[i]=M3f[i][lane];
//   m3b[i]=M3f[i][64+j]. Outputs written straight from registers.
__global__ __launch_bounds__(256) void glmlp_pairs(
    const float* __restrict__ mat, const float* __restrict__ ws,
    float* __restrict__ out)
{
    const int t = threadIdx.x;
    const int lane = t & 63;
    const int r = blockIdx.x * 4 + (t >> 6);   // this wave's row
    const int jj = lane & 31;
    const int wbase = r & ~(GS - 1);           // b * GS
    const float* __restrict__ W = ws + W_OFF;

    // ballots of the mask row (4 x 64 entries, coalesced loads)
    const unsigned long long bal0 = __ballot(mat[r * GS +   0 + lane] != 0.f);
    const unsigned long long bal1 = __ballot(mat[r * GS +  64 + lane] != 0.f);
    const unsigned long long bal2 = __ballot(mat[r * GS + 128 + lane] != 0.f);
    const unsigned long long bal3 = __ballot(mat[r * GS + 192 + lane] != 0.f);

    // register-resident folded weights (coalesced L2-hot loads, once per wave)
    float m2col[I1];                    // 64 VGPR
    #pragma unroll
    for (int s = 0; s < I1; ++s)
        m2col[s] = ws[M2F_OFF + s * I2 + jj];
    float m3a[I2], m3b[I2];             // 64 VGPR
    #pragma unroll
    for (int i = 0; i < I2; ++i) {
        m3a[i] = ws[M3F_OFF + i * PK + lane];
        m3b[i] = ws[M3F_OFF + i * PK + 64 + jj];
    }
    const float ux  = ws[U_OFF + r * I1 + lane] + ws[C1_OFF + lane];
    const float c2j = ws[C2_OFF + jj];
    const float c30 = ws[C3_OFF + lane];
    const float c31 = ws[C3_OFF + 64 + jj];

    // scalar iterator over active y's (wave-uniform state)
    unsigned long long cur = bal0;
    int c = 0;
    auto advance = [&]() -> int {
        while (cur == 0ULL) {
            ++c;
            if (c == 1)      cur = bal1;
            else if (c == 2) cur = bal2;
            else if (c == 3) cur = bal3;
            else             return -1;
        }
        const int b = __builtin_ctzll(cur);
        cur &= cur - 1;
        return (c << 6) + b;
    };

    float acc0 = 0.f, acc1 = 0.f;

    int y = advance();
    float wv = (y >= 0) ? W[(wbase + y) * I1 + lane] : 0.f;
    while (y >= 0) {
        const int yn = advance();
        const float wvn = (yn >= 0) ? W[(wbase + yn) * I1 + lane] : 0.f;

        // Layer 1 (register): lane holds H1[lane]
        const float h1 = fmaxf(ux + wv, 0.f);

        // Layer 2: full dot for column jj via 64 uniform readlane broadcasts;
        // 4 interleaved chains (dep 16).
        float a0 = 0.f, a1 = 0.f, a2 = 0.f, a3 = 0.f;
        #pragma unroll
        for (int s = 0; s < I1; s += 4) {
            a0 = fmaf(rdlane(h1, s + 0), m2col[s + 0], a0);
            a1 = fmaf(rdlane(h1, s + 1), m2col[s + 1], a1);
            a2 = fmaf(rdlane(h1, s + 2), m2col[s + 2], a2);
            a3 = fmaf(rdlane(h1, s + 3), m2col[s + 3], a3);
        }
        // lane l holds H2[l & 31] (duplicated across halves)
        const float h2 = fmaxf((a0 + a1) + (a2 + a3) + c2j, 0.f);

        // Layer 3: 32 uniform broadcasts of H2[i] (lane i holds H2[i], i<32);
        // serves both outputs k0=lane, k1=64+jj. Dual chains each.
        float d0a = c30, d0b = 0.f, d1a = c31, d1b = 0.f;
        #pragma unroll
        for (int i = 0; i < I2; i += 2) {
            const float he = rdlane(h2, i);
            const float ho = rdlane(h2, i + 1);
            d0a = fmaf(he, m3a[i],     d0a);
            d0b = fmaf(ho, m3a[i + 1], d0b);
            d1a = fmaf(he, m3b[i],     d1a);
            d1b = fmaf(ho, m3b[i + 1], d1b);
        }
        acc0 += fmaxf(d0a + d0b, 0.f);
        acc1 += fmaxf(d1a + d1b, 0.f);

        y = yn;
        wv = wvn;
    }

    // write outputs straight from registers (no reduction needed: wave owns row)
    {
        const float v0 = fminf(fmaxf(acc0 * KDIV_INV, -1.f), 1.f);
        out[r * PARAM + KC + lane] = v0;
        if (lane < 32) {
            const float v1 = fminf(fmaxf(acc1 * KDIV_INV, -1.f), 1.f);
            out[r * PARAM + KC + 64 + lane] = v1;
        }
    }
}

extern "C" void kernel_launch(void* const* d_in, const int* in_sizes, int n_in,
                              void* d_out, int out_size, void* d_ws, size_t ws_size,
                              hipStream_t stream) {
    const float* mat = (const float*)d_in[0];
    const float* val = (const float*)d_in[1];
    const float* M1  = (const float*)d_in[2];
    const float* B1  = (const float*)d_in[3];
    const float* M2  = (const float*)d_in[4];
    const float* B2  = (const float*)d_in[5];
    const float* M3  = (const float*)d_in[6];
    const float* B3  = (const float*)d_in[7];
    const float* g1  = (const float*)d_in[8];
    const float* b1  = (const float*)d_in[9];
    const float* m1  = (const float*)d_in[10];
    const float* v1  = (const float*)d_in[11];
    const float* g2  = (const float*)d_in[12];
    const float* b2  = (const float*)d_in[13];
    const float* m2  = (const float*)d_in[14];
    const float* v2  = (const float*)d_in[15];
    const float* g3  = (const float*)d_in[16];
    const float* b3  = (const float*)d_in[17];
    const float* m3  = (const float*)d_in[18];
    const float* v3  = (const float*)d_in[19];

    float* ws  = (float*)d_ws;
    float* out = (float*)d_out;

    hipLaunchKernelGGL(glmlp_precompute, dim3(NROWS + 1), dim3(256), 0, stream,
                       val, M1, B1, M2, B2, M3, B3,
                       g1, b1, m1, v1, g2, b2, m2, v2, g3, b3, m3, v3,
                       ws, out);

    hipLaunchKernelGGL(glmlp_pairs, dim3(NROWS / 4), dim3(256), 0, stream,
                       mat, ws, out);
}

// Round 10
// 113.646 us; speedup vs baseline: 1.0777x; 1.0777x over previous
//
#include <hip/hip_runtime.h>

// Problem constants (fixed by reference)
#define GS    256
#define PARAM 128
#define KC    32
#define I1    64
#define I2    32
#define PK    96        // PARAM - KC
#define B_    4
#define NROWS (B_ * GS) // 1024
#define EPS   1e-3f
#define KDIV_INV (1.0f / 16.0f)

// Workspace layout (float offsets)
constexpr int U_OFF   = 0;                   // NROWS*I1
constexpr int W_OFF   = NROWS * I1;
constexpr int M2F_OFF = 2 * NROWS * I1;      // I1*I2
constexpr int C2_OFF  = M2F_OFF + I1 * I2;   // I2
constexpr int M3F_OFF = C2_OFF + I2;         // I2*PK
constexpr int C3_OFF  = M3F_OFF + I2 * PK;   // PK
constexpr int C1_OFF  = C3_OFF + PK;         // I1

__device__ __forceinline__ float rdlane(float v, int l) {
    return __uint_as_float(__builtin_amdgcn_readlane(__float_as_uint(v), l));
}

// Kernel A: one block per row. 256 thr = 64 i-lanes x 4 quarter-dots.
// u = val.(M1top - M1bot) = T - W; compute T and W (1 load per MAC each).
__global__ __launch_bounds__(256) void glmlp_precompute(
    const float* __restrict__ val, const float* __restrict__ M1,
    const float* __restrict__ B1,
    const float* __restrict__ M2, const float* __restrict__ B2,
    const float* __restrict__ M3, const float* __restrict__ B3,
    const float* __restrict__ g1, const float* __restrict__ b1,
    const float* __restrict__ m1, const float* __restrict__ v1,
    const float* __restrict__ g2, const float* __restrict__ b2,
    const float* __restrict__ m2, const float* __restrict__ v2,
    const float* __restrict__ g3, const float* __restrict__ b3,
    const float* __restrict__ m3, const float* __restrict__ v3,
    float* __restrict__ ws, float* __restrict__ out)
{
    const int blk = blockIdx.x;
    const int t = threadIdx.x;

    if (blk < NROWS) {
        __shared__ float vrow[PARAM];
        __shared__ float red[4][I1];
        const int r = blk;
        if (t < PARAM) vrow[t] = val[r * PARAM + t];
        // exact copy: con = val[:, :, :KC] (direct from global; no barrier dep)
        if (t < KC) out[r * PARAM + t] = val[r * PARAM + t];
        __syncthreads();

        const int i = t & (I1 - 1);
        const int q = t >> 6;                         // 0..3
        // q=0,1 -> T (M1 top half); q=2,3 -> W (M1 bottom half)
        const float* __restrict__ Mb = M1 + ((q >> 1) ? (PARAM * I1) : 0);
        const int p0 = (q & 1) * 64;
        float aa = 0.f, bb = 0.f;                     // dual chains (dep 32)
        #pragma unroll 8
        for (int p = 0; p < 64; p += 2) {
            aa = fmaf(vrow[p0 + p],     Mb[(p0 + p) * I1 + i],     aa);
            bb = fmaf(vrow[p0 + p + 1], Mb[(p0 + p + 1) * I1 + i], bb);
        }
        red[q][i] = aa + bb;
        __syncthreads();

        if (q == 0) {
            const float T  = red[0][i] + red[1][i];
            const float Wv = red[2][i] + red[3][i];
            const float s1 = g1[i] * rsqrtf(v1[i] + EPS);
            ws[U_OFF + r * I1 + i] = (T - Wv) * s1;
            ws[W_OFF + r * I1 + i] = Wv * s1;
        }
    } else {
        // BN folding block
        if (t < I1) {
            const float s1 = g1[t] * rsqrtf(v1[t] + EPS);
            ws[C1_OFF + t] = B1[t] * s1 + b1[t] - m1[t] * s1;
        }
        if (t < I2) {
            const float s2 = g2[t] * rsqrtf(v2[t] + EPS);
            ws[C2_OFF + t] = B2[t] * s2 + b2[t] - m2[t] * s2;
        }
        if (t < PK) {
            const float s3 = g3[t] * rsqrtf(v3[t] + EPS);
            ws[C3_OFF + t] = B3[t] * s3 + b3[t] - m3[t] * s3;
        }
        for (int idx = t; idx < I1 * I2; idx += 256) {
            const int j = idx & (I2 - 1);
            const float s2 = g2[j] * rsqrtf(v2[j] + EPS);
            ws[M2F_OFF + idx] = M2[idx] * s2;
        }
        for (int idx = t; idx < I2 * PK; idx += 256) {
            const int k = idx % PK;
            const float s3 = g3[k] * rsqrtf(v3[k] + EPS);
            ws[M3F_OFF + idx] = M3[idx] * s3;
        }
    }
}

// Kernel B: one block per row, 128 threads = 2 WAVES. 2048 waves total at
// 2 waves/SIMD (VGPR-capped residency) -> ALL blocks resident in one round
// (R9's wave-per-row gave only 1 wave/SIMD -> latency fully exposed -> 12 us
// regression; R8's 4-wave blocks needed 2 residency rounds).
// Mask compaction via __ballot + scalar ctz iterator (no atomics, no acty).
// Waves take alternating active entries. Cross-lane via v_readlane (SGPR
// broadcast); weights register-resident. LDS = 384 B partial + 1 barrier.
__global__ __launch_bounds__(128) void glmlp_pairs(
    const float* __restrict__ mat, const float* __restrict__ ws,
    float* __restrict__ out)
{
    __shared__ float partial[PK];       // wave 1's partials, 384 B

    const int t = threadIdx.x;
    const int lane = t & 63;
    const int w = t >> 6;               // wave id 0..1
    const int r = blockIdx.x;
    const int jj = lane & 31;
    const int wbase = r & ~(GS - 1);    // b * GS
    const float* __restrict__ W = ws + W_OFF;

    // ballots of the mask row (4 x 64 entries, coalesced loads)
    const unsigned long long bal0 = __ballot(mat[r * GS +   0 + lane] != 0.f);
    const unsigned long long bal1 = __ballot(mat[r * GS +  64 + lane] != 0.f);
    const unsigned long long bal2 = __ballot(mat[r * GS + 128 + lane] != 0.f);
    const unsigned long long bal3 = __ballot(mat[r * GS + 192 + lane] != 0.f);

    // register-resident folded weights (coalesced L2-hot loads, once per wave)
    float m2col[I1];                    // 64 VGPR
    #pragma unroll
    for (int s = 0; s < I1; ++s)
        m2col[s] = ws[M2F_OFF + s * I2 + jj];
    float m3a[I2], m3b[I2];             // 64 VGPR
    #pragma unroll
    for (int i = 0; i < I2; ++i) {
        m3a[i] = ws[M3F_OFF + i * PK + lane];
        m3b[i] = ws[M3F_OFF + i * PK + 64 + jj];
    }
    const float ux  = ws[U_OFF + r * I1 + lane] + ws[C1_OFF + lane];
    const float c2j = ws[C2_OFF + jj];
    const float c30 = ws[C3_OFF + lane];
    const float c31 = ws[C3_OFF + 64 + jj];

    // scalar iterator over active y's (wave-uniform SGPR state)
    unsigned long long cur = bal0;
    int c = 0;
    auto advance = [&]() -> int {
        while (cur == 0ULL) {
            ++c;
            if (c == 1)      cur = bal1;
            else if (c == 2) cur = bal2;
            else if (c == 3) cur = bal3;
            else             return -1;
        }
        const int b = __builtin_ctzll(cur);
        cur &= cur - 1;
        return (c << 6) + b;
    };
    // wave w takes active entries with index ≡ w (mod 2)
    auto advance_mine = [&]() -> int {
        const int skip = advance();     // partner wave's entry
        if (skip < 0) return -1;
        return advance();
    };

    float acc0 = 0.f, acc1 = 0.f;

    int y = advance();                  // entry 0
    if (w == 1 && y >= 0) y = advance();// wave 1 starts at entry 1
    float wv = (y >= 0) ? W[(wbase + y) * I1 + lane] : 0.f;
    while (y >= 0) {
        const int yn = advance_mine();
        const float wvn = (yn >= 0) ? W[(wbase + yn) * I1 + lane] : 0.f;

        // Layer 1 (register): lane holds H1[lane]
        const float h1 = fmaxf(ux + wv, 0.f);

        // Layer 2: full dot for column jj via 64 uniform readlane broadcasts;
        // 4 interleaved chains (dep 16).
        float a0 = 0.f, a1 = 0.f, a2 = 0.f, a3 = 0.f;
        #pragma unroll
        for (int s = 0; s < I1; s += 4) {
            a0 = fmaf(rdlane(h1, s + 0), m2col[s + 0], a0);
            a1 = fmaf(rdlane(h1, s + 1), m2col[s + 1], a1);
            a2 = fmaf(rdlane(h1, s + 2), m2col[s + 2], a2);
            a3 = fmaf(rdlane(h1, s + 3), m2col[s + 3], a3);
        }
        // lane l holds H2[l & 31] (duplicated across halves)
        const float h2 = fmaxf((a0 + a1) + (a2 + a3) + c2j, 0.f);

        // Layer 3: 32 uniform broadcasts of H2[i] (lane i holds H2[i], i<32);
        // serves both outputs k0=lane, k1=64+jj. Dual chains each.
        float d0a = c30, d0b = 0.f, d1a = c31, d1b = 0.f;
        #pragma unroll
        for (int i = 0; i < I2; i += 2) {
            const float he = rdlane(h2, i);
            const float ho = rdlane(h2, i + 1);
            d0a = fmaf(he, m3a[i],     d0a);
            d0b = fmaf(ho, m3a[i + 1], d0b);
            d1a = fmaf(he, m3b[i],     d1a);
            d1b = fmaf(ho, m3b[i + 1], d1b);
        }
        acc0 += fmaxf(d0a + d0b, 0.f);
        acc1 += fmaxf(d1a + d1b, 0.f);

        y = yn;
        wv = wvn;
    }

    // cross-wave reduce (384 B LDS, one barrier), then register write-out
    if (w == 1) {
        partial[lane] = acc0;
        if (lane < 32) partial[64 + lane] = acc1;
    }
    __syncthreads();
    if (w == 0) {
        const float v0 = fminf(fmaxf((acc0 + partial[lane]) * KDIV_INV, -1.f), 1.f);
        out[r * PARAM + KC + lane] = v0;
        if (lane < 32) {
            const float v1 =
                fminf(fmaxf((acc1 + partial[64 + lane]) * KDIV_INV, -1.f), 1.f);
            out[r * PARAM + KC + 64 + lane] = v1;
        }
    }
}

extern "C" void kernel_launch(void* const* d_in, const int* in_sizes, int n_in,
                              void* d_out, int out_size, void* d_ws, size_t ws_size,
                              hipStream_t stream) {
    const float* mat = (const float*)d_in[0];
    const float* val = (const float*)d_in[1];
    const float* M1  = (const float*)d_in[2];
    const float* B1  = (const float*)d_in[3];
    const float* M2  = (const float*)d_in[4];
    const float* B2  = (const float*)d_in[5];
    const float* M3  = (const float*)d_in[6];
    const float* B3  = (const float*)d_in[7];
    const float* g1  = (const float*)d_in[8];
    const float* b1  = (const float*)d_in[9];
    const float* m1  = (const float*)d_in[10];
    const float* v1  = (const float*)d_in[11];
    const float* g2  = (const float*)d_in[12];
    const float* b2  = (const float*)d_in[13];
    const float* m2  = (const float*)d_in[14];
    const float* v2  = (const float*)d_in[15];
    const float* g3  = (const float*)d_in[16];
    const float* b3  = (const float*)d_in[17];
    const float* m3  = (const float*)d_in[18];
    const float* v3  = (const float*)d_in[19];

    float* ws  = (float*)d_ws;
    float* out = (float*)d_out;

    hipLaunchKernelGGL(glmlp_precompute, dim3(NROWS + 1), dim3(256), 0, stream,
                       val, M1, B1, M2, B2, M3, B3,
                       g1, b1, m1, v1, g2, b2, m2, v2, g3, b3, m3, v3,
                       ws, out);

    hipLaunchKernelGGL(glmlp_pairs, dim3(NROWS), dim3(128), 0, stream,
                       mat, ws, out);
}

// Round 12
// 111.304 us; speedup vs baseline: 1.1004x; 1.0210x over previous
//
#include <hip/hip_runtime.h>

// Problem constants (fixed by reference)
#define GS    256
#define PARAM 128
#define KC    32
#define I1    64
#define I2    32
#define PK    96        // PARAM - KC
#define B_    4
#define NROWS (B_ * GS) // 1024
#define EPS   1e-3f
#define KDIV_INV (1.0f / 16.0f)

// Workspace layout (float offsets): only U and W survive.
constexpr int U_OFF = 0;              // NROWS*I1
constexpr int W_OFF = NROWS * I1;     // NROWS*I1

__device__ __forceinline__ float rdlane(float v, int l) {
    return __uint_as_float(__builtin_amdgcn_readlane(__float_as_uint(v), l));
}

// Kernel A: one block per row (1024 blocks; no fold block — B folds BN on the
// fly). 256 thr = 64 i-lanes x 4 quarter-dots.
// u = val.(M1top - M1bot) = T - W; compute T and W (1 load per MAC each).
__global__ __launch_bounds__(256) void glmlp_precompute(
    const float* __restrict__ val, const float* __restrict__ M1,
    const float* __restrict__ g1, const float* __restrict__ v1,
    float* __restrict__ ws, float* __restrict__ out)
{
    __shared__ float vrow[PARAM];
    __shared__ float red[4][I1];
    const int r = blockIdx.x;
    const int t = threadIdx.x;

    if (t < PARAM) vrow[t] = val[r * PARAM + t];
    // exact copy: con = val[:, :, :KC] (direct from global; no barrier dep)
    if (t < KC) out[r * PARAM + t] = val[r * PARAM + t];
    __syncthreads();

    const int i = t & (I1 - 1);
    const int q = t >> 6;                         // 0..3
    // q=0,1 -> T (M1 top half); q=2,3 -> W (M1 bottom half)
    const float* __restrict__ Mb = M1 + ((q >> 1) ? (PARAM * I1) : 0);
    const int p0 = (q & 1) * 64;
    float aa = 0.f, bb = 0.f;                     // dual chains (dep 32)
    #pragma unroll 8
    for (int p = 0; p < 64; p += 2) {
        aa = fmaf(vrow[p0 + p],     Mb[(p0 + p) * I1 + i],     aa);
        bb = fmaf(vrow[p0 + p + 1], Mb[(p0 + p + 1) * I1 + i], bb);
    }
    red[q][i] = aa + bb;
    __syncthreads();

    if (q == 0) {
        const float T  = red[0][i] + red[1][i];
        const float Wv = red[2][i] + red[3][i];
        const float s1 = g1[i] * rsqrtf(v1[i] + EPS);
        ws[U_OFF + r * I1 + i] = (T - Wv) * s1;   // u' (c1 added in B)
        ws[W_OFF + r * I1 + i] = Wv * s1;         // w'
    }
}

// Kernel B: one block per row, 256 threads = 4 waves; wave w owns active
// entries with index ≡ w (mod 4). Ballot+ctz scalar iterator (SGPR state, no
// atomics/LDS compaction). All cross-lane via v_readlane (SGPR broadcast).
// BN2/BN3 folded on the fly into register-resident weights (no fold pass).
// LDS = 1.5 KB partials + 1 barrier.
__global__ __launch_bounds__(256) void glmlp_pairs(
    const float* __restrict__ mat, const float* __restrict__ ws,
    const float* __restrict__ M2, const float* __restrict__ B2,
    const float* __restrict__ M3, const float* __restrict__ B3,
    const float* __restrict__ B1, const float* __restrict__ g1,
    const float* __restrict__ b1, const float* __restrict__ m1,
    const float* __restrict__ v1,
    const float* __restrict__ g2, const float* __restrict__ b2,
    const float* __restrict__ m2, const float* __restrict__ v2,
    const float* __restrict__ g3, const float* __restrict__ b3,
    const float* __restrict__ m3, const float* __restrict__ v3,
    float* __restrict__ out)
{
    __shared__ float partial[4][PK];    // 1.5 KB

    const int t = threadIdx.x;
    const int lane = t & 63;
    const int w = t >> 6;               // wave id 0..3
    const int r = blockIdx.x;
    const int jj = lane & 31;
    const int wbase = r & ~(GS - 1);    // b * GS
    const float* __restrict__ W = ws + W_OFF;

    // ballots of the mask row (4 x 64 entries, coalesced loads)
    const unsigned long long bal0 = __ballot(mat[r * GS +   0 + lane] != 0.f);
    const unsigned long long bal1 = __ballot(mat[r * GS +  64 + lane] != 0.f);
    const unsigned long long bal2 = __ballot(mat[r * GS + 128 + lane] != 0.f);
    const unsigned long long bal3 = __ballot(mat[r * GS + 192 + lane] != 0.f);

    // BN-folded weights straight into registers (fold math == validated R2 path)
    const float s2j = g2[jj] * rsqrtf(v2[jj] + EPS);
    float m2col[I1];                    // 64 VGPR
    #pragma unroll
    for (int s = 0; s < I1; ++s)
        m2col[s] = M2[s * I2 + jj] * s2j;
    const float c2j = (B2[jj] - m2[jj]) * s2j + b2[jj];

    const float s3l = g3[lane] * rsqrtf(v3[lane] + EPS);
    const float s3h = g3[64 + jj] * rsqrtf(v3[64 + jj] + EPS);
    float m3a[I2], m3b[I2];             // 64 VGPR
    #pragma unroll
    for (int i = 0; i < I2; ++i) {
        m3a[i] = M3[i * PK + lane] * s3l;
        m3b[i] = M3[i * PK + 64 + jj] * s3h;
    }
    const float c30 = (B3[lane] - m3[lane]) * s3l + b3[lane];
    const float c31 = (B3[64 + jj] - m3[64 + jj]) * s3h + b3[64 + jj];

    const float s1l = g1[lane] * rsqrtf(v1[lane] + EPS);
    const float c1l = (B1[lane] - m1[lane]) * s1l + b1[lane];
    const float ux  = ws[U_OFF + r * I1 + lane] + c1l;

    // scalar iterator over active y's (wave-uniform SGPR state)
    unsigned long long cur = bal0;
    int c = 0;
    auto advance = [&]() -> int {
        while (cur == 0ULL) {
            ++c;
            if (c == 1)      cur = bal1;
            else if (c == 2) cur = bal2;
            else if (c == 3) cur = bal3;
            else             return -1;
        }
        const int b = __builtin_ctzll(cur);
        cur &= cur - 1;
        return (c << 6) + b;
    };

    float acc0 = 0.f, acc1 = 0.f;

    // wave w starts at active entry w, strides by 4
    int y = advance();
    for (int s = 0; s < w && y >= 0; ++s) y = advance();
    float wv = (y >= 0) ? W[(wbase + y) * I1 + lane] : 0.f;
    while (y >= 0) {
        int yn = advance();
        for (int s = 0; s < 3 && yn >= 0; ++s) yn = advance();
        const float wvn = (yn >= 0) ? W[(wbase + yn) * I1 + lane] : 0.f;

        // Layer 1 (register): lane holds H1[lane]
        const float h1 = fmaxf(ux + wv, 0.f);

        // Layer 2: full dot for column jj via 64 uniform readlane broadcasts;
        // 4 interleaved chains (dep 16).
        float a0 = 0.f, a1 = 0.f, a2 = 0.f, a3 = 0.f;
        #pragma unroll
        for (int s = 0; s < I1; s += 4) {
            a0 = fmaf(rdlane(h1, s + 0), m2col[s + 0], a0);
            a1 = fmaf(rdlane(h1, s + 1), m2col[s + 1], a1);
            a2 = fmaf(rdlane(h1, s + 2), m2col[s + 2], a2);
            a3 = fmaf(rdlane(h1, s + 3), m2col[s + 3], a3);
        }
        // lane l holds H2[l & 31] (duplicated across halves)
        const float h2 = fmaxf((a0 + a1) + (a2 + a3) + c2j, 0.f);

        // Layer 3: 32 uniform broadcasts of H2[i] (lane i holds H2[i], i<32);
        // serves both outputs k0=lane, k1=64+jj. Dual chains each.
        float d0a = c30, d0b = 0.f, d1a = c31, d1b = 0.f;
        #pragma unroll
        for (int i = 0; i < I2; i += 2) {
            const float he = rdlane(h2, i);
            const float ho = rdlane(h2, i + 1);
            d0a = fmaf(he, m3a[i],     d0a);
            d0b = fmaf(ho, m3a[i + 1], d0b);
            d1a = fmaf(he, m3b[i],     d1a);
            d1b = fmaf(ho, m3b[i + 1], d1b);
        }
        acc0 += fmaxf(d0a + d0b, 0.f);
        acc1 += fmaxf(d1a + d1b, 0.f);

        y = yn;
        wv = wvn;
    }

    partial[w][lane] = acc0;
    if (lane < 32) partial[w][64 + lane] = acc1;   // halves hold identical acc1
    __syncthreads();

    if (t < PK) {
        float v = (partial[0][t] + partial[1][t] + partial[2][t] + partial[3][t])
                  * KDIV_INV;
        v = fminf(fmaxf(v, -1.0f), 1.0f);
        out[r * PARAM + KC + t] = v;
    }
}

extern "C" void kernel_launch(void* const* d_in, const int* in_sizes, int n_in,
                              void* d_out, int out_size, void* d_ws, size_t ws_size,
                              hipStream_t stream) {
    const float* mat = (const float*)d_in[0];
    const float* val = (const float*)d_in[1];
    const float* M1  = (const float*)d_in[2];
    const float* B1  = (const float*)d_in[3];
    const float* M2  = (const float*)d_in[4];
    const float* B2  = (const float*)d_in[5];
    const float* M3  = (const float*)d_in[6];
    const float* B3  = (const float*)d_in[7];
    const float* g1  = (const float*)d_in[8];
    const float* b1  = (const float*)d_in[9];
    const float* m1  = (const float*)d_in[10];
    const float* v1  = (const float*)d_in[11];
    const float* g2  = (const float*)d_in[12];
    const float* b2  = (const float*)d_in[13];
    const float* m2  = (const float*)d_in[14];
    const float* v2  = (const float*)d_in[15];
    const float* g3  = (const float*)d_in[16];
    const float* b3  = (const float*)d_in[17];
    const float* m3  = (const float*)d_in[18];
    const float* v3  = (const float*)d_in[19];

    float* ws  = (float*)d_ws;
    float* out = (float*)d_out;

    hipLaunchKernelGGL(glmlp_precompute, dim3(NROWS), dim3(256), 0, stream,
                       val, M1, g1, v1, ws, out);

    hipLaunchKernelGGL(glmlp_pairs, dim3(NROWS), dim3(256), 0, stream,
                       mat, ws, M2, B2, M3, B3,
                       B1, g1, b1, m1, v1, g2, b2, m2, v2, g3, b3, m3, v3,
                       out);
}